// Round 7
// baseline (688.684 us; speedup 1.0000x reference)
//
#include <hip/hip_runtime.h>
#include <cstdint>
#include <cstddef>

// Sizes (fixed by the problem)
#define B_ 256
#define S_ 128
#define F_ 128
#define H_ 512
#define C_ 64
#define L_ 16
// 4H = 2048, 3H = 1536

typedef __attribute__((ext_vector_type(8))) short short8;   // 8 x bf16 (4 VGPRs) MFMA A/B frag
typedef __attribute__((ext_vector_type(4))) float f4;       // MFMA C/D frag
typedef __attribute__((ext_vector_type(4))) unsigned int u4;

__device__ __forceinline__ unsigned short f2bf(float f) {   // fp32 -> bf16 RNE
  union { float f; unsigned u; } v; v.f = f;
  unsigned r = v.u + 0x7fffu + ((v.u >> 16) & 1u);
  return (unsigned short)(r >> 16);
}
__device__ __forceinline__ float sigmoid_(float x) { return 1.0f / (1.0f + __expf(-x)); }
__device__ __forceinline__ float tanh_(float x) {
  x = fminf(15.f, fmaxf(-15.f, x));           // clamp: avoid inf/inf
  float e = __expf(2.f * x);
  return (e - 1.f) / (e + 1.f);
}

// ---------------------------------------------------------------------------
// Pre-pack W_hh / W_ih into MFMA B-fragment order (bf16) + combined bias.
// Tiling: 8 g-blocks (64 h-cols each) x 4 waves x 4 gates.
//   frag(g, w, gate, kit): col = gate*512 + g*64 + w*16 + (lane&15)
//                          k   = kit*32 + ((lane>>4)<<3) + j
// ---------------------------------------------------------------------------
__global__ void prepack_w(const float* __restrict__ W_hh, const float* __restrict__ W_ih,
                          const float* __restrict__ b_ih, const float* __restrict__ b_hh,
                          unsigned short* __restrict__ Wpk, unsigned short* __restrict__ Wipk,
                          float* __restrict__ bc) {
  int t = blockIdx.x * blockDim.x + threadIdx.x;
  if (t < 131072) {                      // W_hh: 8 g * 4 w * 4 gate * 16 kit * 64 lanes
    int lane = t & 63, r = t >> 6;
    int kit = r & 15, z = r >> 4;        // z = g*16 + w*4 + gate
    int gate = z & 3, w = (z >> 2) & 3, g = z >> 4;
    int col = gate * 512 + g * 64 + w * 16 + (lane & 15);
    int k0 = kit * 32 + ((lane >> 4) << 3);
#pragma unroll
    for (int j = 0; j < 8; j++)
      Wpk[t * 8 + j] = f2bf(W_hh[(k0 + j) * 2048 + col]);
  } else if (t < 131072 + 32768) {       // W_ih: 8 g * 4 w * 4 gate * 4 kit * 64 lanes
    int t2 = t - 131072;
    int lane = t2 & 63, r = t2 >> 6;
    int kit = r & 3, z = r >> 2;         // z = g*16 + w*4 + gate
    int gate = z & 3, w = (z >> 2) & 3, g = z >> 4;
    int col = gate * 512 + g * 64 + w * 16 + (lane & 15);
    int k0 = kit * 32 + ((lane >> 4) << 3);
#pragma unroll
    for (int j = 0; j < 8; j++)
      Wipk[t2 * 8 + j] = f2bf(W_ih[(k0 + j) * 2048 + col]);
  } else if (t < 131072 + 32768 + 2048) {
    int i = t - 131072 - 32768;
    bc[i] = b_ih[i] + b_hh[i];           // b_ih + b_hh folded together
  }
}

// ---------------------------------------------------------------------------
// Pre-pack x into fragment-major bf16.
// ---------------------------------------------------------------------------
__global__ void prepack_x(const float* __restrict__ x, unsigned short* __restrict__ xfr) {
  int o8 = blockIdx.x * blockDim.x + threadIdx.x;   // 524288 chunks
  int m = o8 & 15, kb = (o8 >> 4) & 15, Rg = (o8 >> 8) & 15, s = o8 >> 12;
  int b = Rg * 16 + m;
  const float* src = x + (b * S_ + s) * F_ + kb * 8;
  unsigned short* dst = xfr + o8 * 8;
#pragma unroll
  for (int j = 0; j < 8; j++) dst[j] = f2bf(src[j]);
}

// ---------------------------------------------------------------------------
// Context gate, stage 1: hid1 = relu(context @ cg_w1 + cg_b1)   [256 x 512]
// ---------------------------------------------------------------------------
__global__ void ctx1_kernel(const float* __restrict__ context, const float* __restrict__ w1,
                            const float* __restrict__ b1, float* __restrict__ hid1) {
  __shared__ float cc[C_];
  int b = blockIdx.x, t = threadIdx.x;
  if (t < C_) cc[t] = context[b * C_ + t];
  __syncthreads();
  for (int j = t; j < H_; j += 256) {
    float acc = b1[j];
#pragma unroll 8
    for (int k = 0; k < C_; k++) acc = fmaf(cc[k], w1[k * H_ + j], acc);
    hid1[b * H_ + j] = fmaxf(acc, 0.f);
  }
}

// ---------------------------------------------------------------------------
// Context gate, stage 2: ctxg = sigmoid(hid1 @ cg_w2 + cg_b2)   [256 x 1536]
// ---------------------------------------------------------------------------
__global__ void ctx2_kernel(const float* __restrict__ hid1, const float* __restrict__ w2,
                            const float* __restrict__ b2, float* __restrict__ ctxg) {
  __shared__ float hr[4 * H_];
  int r0 = blockIdx.x * 4, t = threadIdx.x;
  for (int i = t; i < 4 * H_; i += 256) hr[i] = hid1[r0 * H_ + i];
  __syncthreads();
  float acc[4][6];
#pragma unroll
  for (int r = 0; r < 4; r++)
#pragma unroll
    for (int i = 0; i < 6; i++) acc[r][i] = 0.f;
  for (int k = 0; k < H_; k++) {
    float w[6];
#pragma unroll
    for (int i = 0; i < 6; i++) w[i] = w2[k * 1536 + t + i * 256];
#pragma unroll
    for (int r = 0; r < 4; r++) {
      float hv = hr[r * H_ + k];
#pragma unroll
      for (int i = 0; i < 6; i++) acc[r][i] = fmaf(hv, w[i], acc[r][i]);
    }
  }
#pragma unroll
  for (int r = 0; r < 4; r++)
#pragma unroll
    for (int i = 0; i < 6; i++) {
      int col = t + i * 256;
      ctxg[(r0 + r) * 1536 + col] = sigmoid_(acc[r][i] + b2[col]);
    }
}

// ---------------------------------------------------------------------------
// Persistent LSTM kernel. Grid = 128 blocks = 16 batch-groups (16 rows) x
// 8 col-blocks (64 h-cols). Wave w owns ALL FOUR gates for its 16 columns ->
// fully in-register cell update.
//
// TAGGED-DWORD h EXCHANGE with SCOUT POLLING:
//   h element stored as dword (tag<<16)|bf16, tag = producing step t + 1
//   (fire-and-forget, no producer drain). Consumers first SCOUT-poll one
//   dword per producer-wave region (32 dwords total, lanes 0..31) until all
//   scout tags == t; only then issue the full 32 KB fragment load + the
//   authoritative all-tag check (straggler -> back to scout). R6's poll
//   refetched the full 32 KB per retry; at 128 concurrent blocks that was
//   L3-bandwidth-bound (FETCH_SIZE 307 MB). Scout retries are 128 B/block:
//   retry period collapses to ~uncontended L3 RTT, full load happens ~once.
//   Correctness unchanged: full check remains the only gate; scout can only
//   delay, never admit stale data. WAR across the 2-buffer reuse is ordered
//   by dataflow causality (tags monotone, unique per reuse).
// ---------------------------------------------------------------------------
__global__ void __launch_bounds__(256, 1) lstm_kernel(
    const unsigned short* __restrict__ xfr, const unsigned short* __restrict__ Wpk,
    const unsigned short* __restrict__ Wipk, const float* __restrict__ bc,
    const float* __restrict__ ctxg, float* __restrict__ hfinal,
    unsigned int* __restrict__ hb0, unsigned int* __restrict__ hb1) {
  __shared__ __align__(16) unsigned short lds_h[8192];   // 16 kit x 512  (16 KB)

  int tid = threadIdx.x, lane = tid & 63, wid = tid >> 6;
  int bt = blockIdx.x >> 3, g = blockIdx.x & 7;

  // --- prologue: resident weight fragments (coalesced 16B/lane loads) ---
  short8 wf[4][16], wfi[4][4];
#pragma unroll
  for (int gate = 0; gate < 4; gate++) {
    const short8* wp = (const short8*)Wpk + (size_t)((g * 16 + wid * 4 + gate) * 16) * 64 + lane;
#pragma unroll
    for (int kit = 0; kit < 16; kit++) wf[gate][kit] = wp[kit * 64];
    const short8* wip = (const short8*)Wipk + (size_t)((g * 16 + wid * 4 + gate) * 4) * 64 + lane;
#pragma unroll
    for (int kit = 0; kit < 4; kit++) wfi[gate][kit] = wip[kit * 64];
  }

  // --- per-lane elementwise constants: lane (q,n) owns rows q*4+r, col n ---
  int q = lane >> 4, n = lane & 15;
  int colglob = g * 64 + wid * 16 + n;
  float ci_[4], cf_[4], co_[4], cst[4] = {0.f, 0.f, 0.f, 0.f};
#pragma unroll
  for (int r = 0; r < 4; r++) {
    int brow = bt * 16 + q * 4 + r;
    ci_[r] = ctxg[brow * 1536 + colglob];
    cf_[r] = ctxg[brow * 1536 + 512 + colglob];
    co_[r] = ctxg[brow * 1536 + 1024 + colglob];
  }
  float bi = bc[colglob], bff = bc[512 + colglob], bgg = bc[1024 + colglob], bo = bc[1536 + colglob];

  // fragment-order store base for this lane's column (units: dwords).
  int hsub = (bt * 16 + (colglob >> 5)) * 512 + ((colglob >> 3) & 3) * 128 + (colglob & 7);

  // scout address component: one sample dword per producer-wave region.
  //   region (sg, sw) covers cols [sg*64+sw*16, +16); sample its first col,
  //   batch-row 0 -> dword (bt*16 + c0>>5)*512 + ((c0>>3)&3)*128 + (c0&7).
  int sg = (lane >> 2) & 7, sw = lane & 3;
  int c0 = sg * 64 + sw * 16;
  int ssub = (bt * 16 + (c0 >> 5)) * 512 + ((c0 >> 3) & 3) * 128 + (c0 & 7);

  for (int t = 0; t < S_; t++) {
    const unsigned int* hread = (t & 1) ? hb1 : hb0;   // double buffer
    unsigned int* hwrite = (t & 1) ? hb0 : hb1;
    unsigned tt = (unsigned)t;          // expected tag on consumed data
    unsigned tt1 = (unsigned)(t + 1);   // tag stored with produced data

    // --- x fragments for step t: plain cached loads (fly under the poll) ---
    u4 xt[4];
#pragma unroll
    for (int kit = 0; kit < 4; kit++)
      xt[kit] = *(const u4*)(xfr + ((size_t)(t * 16 + bt) * 4 + kit) * 512 + lane * 8);

    // --- scout-then-load poll of own 4 kit rows of h(t-1) ---
    u4 a0, a1, a2, a3, a4, a5, a6, a7;
    {
      const unsigned int* sp = hread + ssub;
      const unsigned int* base = hread + (bt * 16 + wid * 4) * 512 + lane * 8;
      const unsigned int* p0 = base;
      const unsigned int* p1 = base + 4;
      const unsigned int* p2 = base + 512;
      const unsigned int* p3 = base + 516;
      const unsigned int* p4 = base + 1024;
      const unsigned int* p5 = base + 1028;
      const unsigned int* p6 = base + 1536;
      const unsigned int* p7 = base + 1540;
      for (;;) {
        // scout: 1 dword/lane (lanes 32..63 mirror 0..31), 128 B per block
        for (;;) {
          unsigned sv;
          asm volatile(
              "global_load_dword %0, %1, off sc0 sc1\n\t"
              "s_waitcnt vmcnt(0)"
              : "=&v"(sv) : "v"(sp) : "memory");
          if (__all((sv >> 16) == tt)) break;
        }
        // full fragment load (32 KB per block, ~once per step)
        asm volatile(
            "global_load_dwordx4 %0, %8, off sc0 sc1\n\t"
            "global_load_dwordx4 %1, %9, off sc0 sc1\n\t"
            "global_load_dwordx4 %2, %10, off sc0 sc1\n\t"
            "global_load_dwordx4 %3, %11, off sc0 sc1\n\t"
            "global_load_dwordx4 %4, %12, off sc0 sc1\n\t"
            "global_load_dwordx4 %5, %13, off sc0 sc1\n\t"
            "global_load_dwordx4 %6, %14, off sc0 sc1\n\t"
            "global_load_dwordx4 %7, %15, off sc0 sc1\n\t"
            "s_waitcnt vmcnt(0)"
            : "=&v"(a0), "=&v"(a1), "=&v"(a2), "=&v"(a3),
              "=&v"(a4), "=&v"(a5), "=&v"(a6), "=&v"(a7)
            : "v"(p0), "v"(p1), "v"(p2), "v"(p3),
              "v"(p4), "v"(p5), "v"(p6), "v"(p7)
            : "memory");
        unsigned bad = 0;
#pragma unroll
        for (int c = 0; c < 4; c++) {
          bad |= (a0[c] >> 16) ^ tt; bad |= (a1[c] >> 16) ^ tt;
          bad |= (a2[c] >> 16) ^ tt; bad |= (a3[c] >> 16) ^ tt;
          bad |= (a4[c] >> 16) ^ tt; bad |= (a5[c] >> 16) ^ tt;
          bad |= (a6[c] >> 16) ^ tt; bad |= (a7[c] >> 16) ^ tt;
        }
        if (__all(bad == 0)) break;   // authoritative gate
      }
    }

    // --- strip tags, pack to bf16x8, stage own 4 rows to LDS ---
    {
      u4 P;
      P.x = (a0[0] & 0xffffu) | (a0[1] << 16);
      P.y = (a0[2] & 0xffffu) | (a0[3] << 16);
      P.z = (a1[0] & 0xffffu) | (a1[1] << 16);
      P.w = (a1[2] & 0xffffu) | (a1[3] << 16);
      *(u4*)(lds_h + (wid * 4 + 0) * 512 + lane * 8) = P;
      P.x = (a2[0] & 0xffffu) | (a2[1] << 16);
      P.y = (a2[2] & 0xffffu) | (a2[3] << 16);
      P.z = (a3[0] & 0xffffu) | (a3[1] << 16);
      P.w = (a3[2] & 0xffffu) | (a3[3] << 16);
      *(u4*)(lds_h + (wid * 4 + 1) * 512 + lane * 8) = P;
      P.x = (a4[0] & 0xffffu) | (a4[1] << 16);
      P.y = (a4[2] & 0xffffu) | (a4[3] << 16);
      P.z = (a5[0] & 0xffffu) | (a5[1] << 16);
      P.w = (a5[2] & 0xffffu) | (a5[3] << 16);
      *(u4*)(lds_h + (wid * 4 + 2) * 512 + lane * 8) = P;
      P.x = (a6[0] & 0xffffu) | (a6[1] << 16);
      P.y = (a6[2] & 0xffffu) | (a6[3] << 16);
      P.z = (a7[0] & 0xffffu) | (a7[1] << 16);
      P.w = (a7[2] & 0xffffu) | (a7[3] << 16);
      *(u4*)(lds_h + (wid * 4 + 3) * 512 + lane * 8) = P;
    }
    __syncthreads();

    // --- x MFMAs ---
    f4 acc[4];
#pragma unroll
    for (int gate = 0; gate < 4; gate++) acc[gate] = (f4){0.f, 0.f, 0.f, 0.f};
#pragma unroll
    for (int kit = 0; kit < 4; kit++) {
      short8 a = __builtin_bit_cast(short8, xt[kit]);
#pragma unroll
      for (int gate = 0; gate < 4; gate++)
        acc[gate] = __builtin_amdgcn_mfma_f32_16x16x32_bf16(a, wfi[gate][kit], acc[gate], 0, 0, 0);
    }

    // --- h MFMAs: all 4 gates for this wave's 16 columns ---
#pragma unroll
    for (int kit = 0; kit < 16; kit++) {
      short8 a = *(const short8*)(lds_h + kit * 512 + lane * 8);
#pragma unroll
      for (int gate = 0; gate < 4; gate++)
        acc[gate] = __builtin_amdgcn_mfma_f32_16x16x32_bf16(a, wf[gate][kit], acc[gate], 0, 0, 0);
    }

    // --- cell update fully in-register (all 4 gates lane-local) ---
    float hv[4];
#pragma unroll
    for (int r = 0; r < 4; r++) {
      float gi = acc[0][r] + bi, gf = acc[1][r] + bff, gc = acc[2][r] + bgg, go = acc[3][r] + bo;
      float iv = ci_[r] * sigmoid_(gi);
      float fv = cf_[r] * sigmoid_(gf);
      float ov = co_[r] * sigmoid_(go);
      float gv = tanh_(gc);
      float c = fv * cst[r] + iv * gv;
      cst[r] = c;
      hv[r] = ov * tanh_(c);
    }

    // --- tagged fragment-order h store: 4 dwords/lane, fire-and-forget ---
#pragma unroll
    for (int r = 0; r < 4; r++) {
      unsigned int* d = hwrite + hsub + (q * 4 + r) * 8;
      unsigned val = (tt1 << 16) | (unsigned)f2bf(hv[r]);
      asm volatile("global_store_dword %0, %1, off sc0 sc1" :: "v"(d), "v"(val) : "memory");
    }
    if (t == S_ - 1) {
#pragma unroll
      for (int r = 0; r < 4; r++)
        hfinal[(bt * 16 + q * 4 + r) * H_ + colglob] = hv[r];
    }
    __syncthreads();   // LDS WAR: all waves done reading lds_h before next stage
  }
}

// ---------------------------------------------------------------------------
// VAE head: mu/lv = h@W + b, z = mu + eps*exp(0.5*lv),
// recon = relu(z@dec_w1+db1)@dec_w2+db2. One block per batch row, all fp32.
// ---------------------------------------------------------------------------
__global__ void post_kernel(const float* __restrict__ hfinal, const float* __restrict__ eps,
                            const float* __restrict__ mu_w, const float* __restrict__ mu_b,
                            const float* __restrict__ lv_w, const float* __restrict__ lv_b,
                            const float* __restrict__ dw1, const float* __restrict__ db1,
                            const float* __restrict__ dw2, const float* __restrict__ db2,
                            float* __restrict__ out) {
  __shared__ float sh[H_], sh1[H_], smu[L_], slv[L_], sz[L_];
  int b = blockIdx.x, t = threadIdx.x;
  for (int i = t; i < H_; i += 256) sh[i] = hfinal[b * H_ + i];
  __syncthreads();
  {
    int o = t >> 3, sub = t & 7, l = o & 15;   // 32 outputs x 8-lane partial dots
    const float* w = (o < 16) ? mu_w : lv_w;
    float acc = 0.f;
    int k0 = sub * 64;
#pragma unroll 8
    for (int k = k0; k < k0 + 64; k++) acc = fmaf(sh[k], w[k * L_ + l], acc);
#pragma unroll
    for (int d = 4; d >= 1; d >>= 1) acc += __shfl_down(acc, d, 8);
    if (sub == 0) {
      if (o < 16) { float v = acc + mu_b[l]; smu[l] = v; out[32768 + b * 16 + l] = v; }
      else        { float v = acc + lv_b[l]; slv[l] = v; out[36864 + b * 16 + l] = v; }
    }
  }
  __syncthreads();
  if (t < L_) sz[t] = smu[t] + eps[b * L_ + t] * __expf(0.5f * slv[t]);
  __syncthreads();
  for (int j = t; j < H_; j += 256) {
    float acc = db1[j];
#pragma unroll
    for (int l = 0; l < L_; l++) acc = fmaf(sz[l], dw1[l * H_ + j], acc);
    sh1[j] = fmaxf(acc, 0.f);
  }
  __syncthreads();
  if (t < F_) {
    float acc = db2[t];
    for (int k = 0; k < H_; k++) acc = fmaf(sh1[k], dw2[k * F_ + t], acc);
    out[b * F_ + t] = acc;
  }
}

// ---------------------------------------------------------------------------
extern "C" void kernel_launch(void* const* d_in, const int* in_sizes, int n_in,
                              void* d_out, int out_size, void* d_ws, size_t ws_size,
                              hipStream_t stream) {
  const float* x      = (const float*)d_in[0];
  const float* ctxin  = (const float*)d_in[1];
  const float* eps    = (const float*)d_in[2];
  const float* W_ih   = (const float*)d_in[3];
  const float* b_ih   = (const float*)d_in[4];
  const float* W_hh   = (const float*)d_in[5];
  const float* b_hh   = (const float*)d_in[6];
  const float* cg_w1  = (const float*)d_in[7];
  const float* cg_b1  = (const float*)d_in[8];
  const float* cg_w2  = (const float*)d_in[9];
  const float* cg_b2  = (const float*)d_in[10];
  const float* mu_w   = (const float*)d_in[11];
  const float* mu_b   = (const float*)d_in[12];
  const float* lv_w   = (const float*)d_in[13];
  const float* lv_b   = (const float*)d_in[14];
  const float* dec_w1 = (const float*)d_in[15];
  const float* dec_b1 = (const float*)d_in[16];
  const float* dec_w2 = (const float*)d_in[17];
  const float* dec_b2 = (const float*)d_in[18];
  float* out = (float*)d_out;

  char* ws = (char*)d_ws;
  size_t off = 0;
  auto alloc = [&](size_t bytes) { char* p = ws + off; off = (off + bytes + 255) & ~(size_t)255; return p; };

  unsigned int* hb0 = (unsigned int*)alloc((size_t)B_ * H_ * 4);  // 512 KB tagged dwords
  unsigned int* hb1 = (unsigned int*)alloc((size_t)B_ * H_ * 4);  // 512 KB
  size_t zero_bytes = off;   // zero tags each launch (tag 0 == valid h(-1)=0)
  unsigned short* xfr  = (unsigned short*)alloc((size_t)B_ * S_ * F_ * 2);  // 8 MB
  unsigned short* Wpk  = (unsigned short*)alloc((size_t)H_ * 2048 * 2);     // 2 MB
  unsigned short* Wipk = (unsigned short*)alloc((size_t)F_ * 2048 * 2);     // 512 KB
  float* bc    = (float*)alloc(2048 * 4);
  float* ctxg  = (float*)alloc((size_t)B_ * 1536 * 4);
  float* hid1  = (float*)alloc((size_t)B_ * H_ * 4);
  float* hfin  = (float*)alloc((size_t)B_ * H_ * 4);
  (void)ws_size; (void)in_sizes; (void)n_in; (void)out_size;

  hipMemsetAsync(d_ws, 0, zero_bytes, stream);   // tagged h buffers

  prepack_w<<<648, 256, 0, stream>>>(W_hh, W_ih, b_ih, b_hh, Wpk, Wipk, bc);
  prepack_x<<<2048, 256, 0, stream>>>(x, xfr);
  ctx1_kernel<<<256, 256, 0, stream>>>(ctxin, cg_w1, cg_b1, hid1);
  ctx2_kernel<<<64, 256, 0, stream>>>(hid1, cg_w2, cg_b2, ctxg);
  lstm_kernel<<<128, 256, 0, stream>>>(xfr, Wpk, Wipk, bc, ctxg, hfin, hb0, hb1);
  post_kernel<<<256, 256, 0, stream>>>(hfin, eps, mu_w, mu_b, lv_w, lv_b,
                                       dec_w1, dec_b1, dec_w2, dec_b2, out);
}

// Round 10
// 650.380 us; speedup vs baseline: 1.0589x; 1.0589x over previous
//
#include <hip/hip_runtime.h>
#include <cstdint>
#include <cstddef>

// Sizes (fixed by the problem)
#define B_ 256
#define S_ 128
#define F_ 128
#define H_ 512
#define C_ 64
#define L_ 16
// 4H = 2048, 3H = 1536

typedef __attribute__((ext_vector_type(8))) short short8;   // 8 x bf16 (4 VGPRs) MFMA A/B frag
typedef __attribute__((ext_vector_type(4))) float f4;       // MFMA C/D frag
typedef __attribute__((ext_vector_type(4))) unsigned int u4;

__device__ __forceinline__ unsigned short f2bf(float f) {   // fp32 -> bf16 RNE
  union { float f; unsigned u; } v; v.f = f;
  unsigned r = v.u + 0x7fffu + ((v.u >> 16) & 1u);
  return (unsigned short)(r >> 16);
}
__device__ __forceinline__ float sigmoid_(float x) { return 1.0f / (1.0f + __expf(-x)); }
__device__ __forceinline__ float tanh_(float x) {
  x = fminf(15.f, fmaxf(-15.f, x));           // clamp: avoid inf/inf
  float e = __expf(2.f * x);
  return (e - 1.f) / (e + 1.f);
}

// ---------------------------------------------------------------------------
// FUSED pre-pass: prepack W_hh/W_ih + bias fold (blocks [0,648)),
// prepack x (blocks [648,2696)), ctx gate stage 1 (blocks [2696,2952)).
// The three parts are mutually independent; fusing saves 2 launches and
// overlaps their execution. Layouts identical to the proven kernels.
//   W frag(g, w, gate, kit): col = gate*512 + g*64 + w*16 + (lane&15)
//                            k   = kit*32 + ((lane>>4)<<3) + j
// ---------------------------------------------------------------------------
__global__ void fused_pre(const float* __restrict__ W_hh, const float* __restrict__ W_ih,
                          const float* __restrict__ b_ih, const float* __restrict__ b_hh,
                          const float* __restrict__ x, const float* __restrict__ context,
                          const float* __restrict__ cg_w1, const float* __restrict__ cg_b1,
                          unsigned short* __restrict__ Wpk, unsigned short* __restrict__ Wipk,
                          float* __restrict__ bc, unsigned short* __restrict__ xfr,
                          float* __restrict__ hid1) {
  int bid = blockIdx.x;
  if (bid < 648) {                       // ---- prepack weights + bias ----
    int t = bid * blockDim.x + threadIdx.x;
    if (t < 131072) {                    // W_hh: 8 g * 4 w * 4 gate * 16 kit * 64 lanes
      int lane = t & 63, r = t >> 6;
      int kit = r & 15, z = r >> 4;      // z = g*16 + w*4 + gate
      int gate = z & 3, w = (z >> 2) & 3, g = z >> 4;
      int col = gate * 512 + g * 64 + w * 16 + (lane & 15);
      int k0 = kit * 32 + ((lane >> 4) << 3);
#pragma unroll
      for (int j = 0; j < 8; j++)
        Wpk[t * 8 + j] = f2bf(W_hh[(k0 + j) * 2048 + col]);
    } else if (t < 131072 + 32768) {     // W_ih: 8 g * 4 w * 4 gate * 4 kit * 64 lanes
      int t2 = t - 131072;
      int lane = t2 & 63, r = t2 >> 6;
      int kit = r & 3, z = r >> 2;       // z = g*16 + w*4 + gate
      int gate = z & 3, w = (z >> 2) & 3, g = z >> 4;
      int col = gate * 512 + g * 64 + w * 16 + (lane & 15);
      int k0 = kit * 32 + ((lane >> 4) << 3);
#pragma unroll
      for (int j = 0; j < 8; j++)
        Wipk[t2 * 8 + j] = f2bf(W_ih[(k0 + j) * 2048 + col]);
    } else if (t < 131072 + 32768 + 2048) {
      int i = t - 131072 - 32768;
      bc[i] = b_ih[i] + b_hh[i];         // b_ih + b_hh folded together
    }
  } else if (bid < 2696) {               // ---- prepack x (fragment-major bf16) ----
    int o8 = (bid - 648) * blockDim.x + threadIdx.x;   // 524288 chunks
    int m = o8 & 15, kb = (o8 >> 4) & 15, Rg = (o8 >> 8) & 15, s = o8 >> 12;
    int b = Rg * 16 + m;
    const float* src = x + (b * S_ + s) * F_ + kb * 8;
    unsigned short* dst = xfr + o8 * 8;
#pragma unroll
    for (int j = 0; j < 8; j++) dst[j] = f2bf(src[j]);
  } else {                               // ---- ctx1: relu(context @ cg_w1 + b1) ----
    __shared__ float cc[C_];
    int b = bid - 2696, t = threadIdx.x;
    if (t < C_) cc[t] = context[b * C_ + t];
    __syncthreads();
    for (int j = t; j < H_; j += 256) {
      float acc = cg_b1[j];
#pragma unroll 8
      for (int k = 0; k < C_; k++) acc = fmaf(cc[k], cg_w1[k * H_ + j], acc);
      hid1[b * H_ + j] = fmaxf(acc, 0.f);
    }
  }
}

// ---------------------------------------------------------------------------
// Context gate, stage 2: ctxg = sigmoid(hid1 @ cg_w2 + cg_b2)   [256 x 1536]
// ---------------------------------------------------------------------------
__global__ void ctx2_kernel(const float* __restrict__ hid1, const float* __restrict__ w2,
                            const float* __restrict__ b2, float* __restrict__ ctxg) {
  __shared__ float hr[4 * H_];
  int r0 = blockIdx.x * 4, t = threadIdx.x;
  for (int i = t; i < 4 * H_; i += 256) hr[i] = hid1[r0 * H_ + i];
  __syncthreads();
  float acc[4][6];
#pragma unroll
  for (int r = 0; r < 4; r++)
#pragma unroll
    for (int i = 0; i < 6; i++) acc[r][i] = 0.f;
  for (int k = 0; k < H_; k++) {
    float w[6];
#pragma unroll
    for (int i = 0; i < 6; i++) w[i] = w2[k * 1536 + t + i * 256];
#pragma unroll
    for (int r = 0; r < 4; r++) {
      float hv = hr[r * H_ + k];
#pragma unroll
      for (int i = 0; i < 6; i++) acc[r][i] = fmaf(hv, w[i], acc[r][i]);
    }
  }
#pragma unroll
  for (int r = 0; r < 4; r++)
#pragma unroll
    for (int i = 0; i < 6; i++) {
      int col = t + i * 256;
      ctxg[(r0 + r) * 1536 + col] = sigmoid_(acc[r][i] + b2[col]);
    }
}

// ---------------------------------------------------------------------------
// Persistent LSTM kernel — EXACT R6 version (harness-proven, 470 us).
// Grid = 128 blocks = 16 batch-groups (16 rows) x 8 col-blocks (64 h-cols).
// Wave w owns ALL FOUR gates for its 16 columns -> in-register cell update.
// TAGGED-DWORD h EXCHANGE (data IS the synchronization):
//   h element stored as dword (tag<<16)|bf16, tag = producing step t + 1,
//   fire-and-forget at device scope (sc0 sc1). Consumers poll their own
//   fragment dwords (self-contained asm: 8x dwordx4 + internal vmcnt(0))
//   until all 32 tags == t. Value+validity are one atomic 4B store -> no
//   flags, no atomics, no store-ack vmcnt. WAR across the 2-buffer reuse is
//   ordered by dataflow causality (tags monotone, unique per reuse).
// NOTE: the R7/R8 XCD-vote L2 fast path was WITHDRAWN — if HW_REG_XCC_ID
// misreports in this container, a false-unanimous vote livelocks (stale L2
// line never invalidated cross-XCD). Device-scope path has no such mode.
// ---------------------------------------------------------------------------
__global__ void __launch_bounds__(256, 1) lstm_kernel(
    const unsigned short* __restrict__ xfr, const unsigned short* __restrict__ Wpk,
    const unsigned short* __restrict__ Wipk, const float* __restrict__ bc,
    const float* __restrict__ ctxg, float* __restrict__ hfinal,
    unsigned int* __restrict__ hb0, unsigned int* __restrict__ hb1) {
  __shared__ __align__(16) unsigned short lds_h[8192];   // 16 kit x 512  (16 KB)

  int tid = threadIdx.x, lane = tid & 63, wid = tid >> 6;
  int bt = blockIdx.x >> 3, g = blockIdx.x & 7;

  // --- prologue: resident weight fragments (coalesced 16B/lane loads) ---
  short8 wf[4][16], wfi[4][4];
#pragma unroll
  for (int gate = 0; gate < 4; gate++) {
    const short8* wp = (const short8*)Wpk + (size_t)((g * 16 + wid * 4 + gate) * 16) * 64 + lane;
#pragma unroll
    for (int kit = 0; kit < 16; kit++) wf[gate][kit] = wp[kit * 64];
    const short8* wip = (const short8*)Wipk + (size_t)((g * 16 + wid * 4 + gate) * 4) * 64 + lane;
#pragma unroll
    for (int kit = 0; kit < 4; kit++) wfi[gate][kit] = wip[kit * 64];
  }

  // --- per-lane elementwise constants: lane (q,n) owns rows q*4+r, col n ---
  int q = lane >> 4, n = lane & 15;
  int colglob = g * 64 + wid * 16 + n;
  float ci_[4], cf_[4], co_[4], cst[4] = {0.f, 0.f, 0.f, 0.f};
#pragma unroll
  for (int r = 0; r < 4; r++) {
    int brow = bt * 16 + q * 4 + r;
    ci_[r] = ctxg[brow * 1536 + colglob];
    cf_[r] = ctxg[brow * 1536 + 512 + colglob];
    co_[r] = ctxg[brow * 1536 + 1024 + colglob];
  }
  float bi = bc[colglob], bff = bc[512 + colglob], bgg = bc[1024 + colglob], bo = bc[1536 + colglob];

  // fragment-order store base for this lane's column (units: dwords).
  //   kit row = colglob>>5 (512 dwords/row); within-row:
  //   ((colglob>>3)&3)*128 + (colglob&7) + (q*4+r)*8
  int hsub = (bt * 16 + (colglob >> 5)) * 512 + ((colglob >> 3) & 3) * 128 + (colglob & 7);

  for (int t = 0; t < S_; t++) {
    const unsigned int* hread = (t & 1) ? hb1 : hb0;   // double buffer
    unsigned int* hwrite = (t & 1) ? hb0 : hb1;
    unsigned tt = (unsigned)t;          // expected tag on consumed data
    unsigned tt1 = (unsigned)(t + 1);   // tag stored with produced data

    // --- x fragments for step t: plain cached loads (fly under the poll) ---
    u4 xt[4];
#pragma unroll
    for (int kit = 0; kit < 4; kit++)
      xt[kit] = *(const u4*)(xfr + ((size_t)(t * 16 + bt) * 4 + kit) * 512 + lane * 8);

    // --- poll own 4 kit rows of h(t-1) until every tag == t ---
    u4 a0, a1, a2, a3, a4, a5, a6, a7;
    {
      const unsigned int* base = hread + (bt * 16 + wid * 4) * 512 + lane * 8;
      const unsigned int* p0 = base;
      const unsigned int* p1 = base + 4;
      const unsigned int* p2 = base + 512;
      const unsigned int* p3 = base + 516;
      const unsigned int* p4 = base + 1024;
      const unsigned int* p5 = base + 1028;
      const unsigned int* p6 = base + 1536;
      const unsigned int* p7 = base + 1540;
      for (;;) {
        asm volatile(
            "global_load_dwordx4 %0, %8, off sc0 sc1\n\t"
            "global_load_dwordx4 %1, %9, off sc0 sc1\n\t"
            "global_load_dwordx4 %2, %10, off sc0 sc1\n\t"
            "global_load_dwordx4 %3, %11, off sc0 sc1\n\t"
            "global_load_dwordx4 %4, %12, off sc0 sc1\n\t"
            "global_load_dwordx4 %5, %13, off sc0 sc1\n\t"
            "global_load_dwordx4 %6, %14, off sc0 sc1\n\t"
            "global_load_dwordx4 %7, %15, off sc0 sc1\n\t"
            "s_waitcnt vmcnt(0)"
            : "=&v"(a0), "=&v"(a1), "=&v"(a2), "=&v"(a3),
              "=&v"(a4), "=&v"(a5), "=&v"(a6), "=&v"(a7)
            : "v"(p0), "v"(p1), "v"(p2), "v"(p3),
              "v"(p4), "v"(p5), "v"(p6), "v"(p7)
            : "memory");
        unsigned bad = 0;
#pragma unroll
        for (int c = 0; c < 4; c++) {
          bad |= (a0[c] >> 16) ^ tt; bad |= (a1[c] >> 16) ^ tt;
          bad |= (a2[c] >> 16) ^ tt; bad |= (a3[c] >> 16) ^ tt;
          bad |= (a4[c] >> 16) ^ tt; bad |= (a5[c] >> 16) ^ tt;
          bad |= (a6[c] >> 16) ^ tt; bad |= (a7[c] >> 16) ^ tt;
        }
        if (__all(bad == 0)) break;
      }
    }

    // --- strip tags, pack to bf16x8, stage own 4 rows to LDS ---
    {
      u4 P;
      P.x = (a0[0] & 0xffffu) | (a0[1] << 16);
      P.y = (a0[2] & 0xffffu) | (a0[3] << 16);
      P.z = (a1[0] & 0xffffu) | (a1[1] << 16);
      P.w = (a1[2] & 0xffffu) | (a1[3] << 16);
      *(u4*)(lds_h + (wid * 4 + 0) * 512 + lane * 8) = P;
      P.x = (a2[0] & 0xffffu) | (a2[1] << 16);
      P.y = (a2[2] & 0xffffu) | (a2[3] << 16);
      P.z = (a3[0] & 0xffffu) | (a3[1] << 16);
      P.w = (a3[2] & 0xffffu) | (a3[3] << 16);
      *(u4*)(lds_h + (wid * 4 + 1) * 512 + lane * 8) = P;
      P.x = (a4[0] & 0xffffu) | (a4[1] << 16);
      P.y = (a4[2] & 0xffffu) | (a4[3] << 16);
      P.z = (a5[0] & 0xffffu) | (a5[1] << 16);
      P.w = (a5[2] & 0xffffu) | (a5[3] << 16);
      *(u4*)(lds_h + (wid * 4 + 2) * 512 + lane * 8) = P;
      P.x = (a6[0] & 0xffffu) | (a6[1] << 16);
      P.y = (a6[2] & 0xffffu) | (a6[3] << 16);
      P.z = (a7[0] & 0xffffu) | (a7[1] << 16);
      P.w = (a7[2] & 0xffffu) | (a7[3] << 16);
      *(u4*)(lds_h + (wid * 4 + 3) * 512 + lane * 8) = P;
    }
    __syncthreads();

    // --- x MFMAs ---
    f4 acc[4];
#pragma unroll
    for (int gate = 0; gate < 4; gate++) acc[gate] = (f4){0.f, 0.f, 0.f, 0.f};
#pragma unroll
    for (int kit = 0; kit < 4; kit++) {
      short8 a = __builtin_bit_cast(short8, xt[kit]);
#pragma unroll
      for (int gate = 0; gate < 4; gate++)
        acc[gate] = __builtin_amdgcn_mfma_f32_16x16x32_bf16(a, wfi[gate][kit], acc[gate], 0, 0, 0);
    }

    // --- h MFMAs: all 4 gates for this wave's 16 columns ---
#pragma unroll
    for (int kit = 0; kit < 16; kit++) {
      short8 a = *(const short8*)(lds_h + kit * 512 + lane * 8);
#pragma unroll
      for (int gate = 0; gate < 4; gate++)
        acc[gate] = __builtin_amdgcn_mfma_f32_16x16x32_bf16(a, wf[gate][kit], acc[gate], 0, 0, 0);
    }

    // --- cell update fully in-register (all 4 gates lane-local) ---
    float hv[4];
#pragma unroll
    for (int r = 0; r < 4; r++) {
      float gi = acc[0][r] + bi, gf = acc[1][r] + bff, gc = acc[2][r] + bgg, go = acc[3][r] + bo;
      float iv = ci_[r] * sigmoid_(gi);
      float fv = cf_[r] * sigmoid_(gf);
      float ov = co_[r] * sigmoid_(go);
      float gv = tanh_(gc);
      float c = fv * cst[r] + iv * gv;
      cst[r] = c;
      hv[r] = ov * tanh_(c);
    }

    // --- tagged fragment-order h store: 4 dwords/lane, fire-and-forget ---
#pragma unroll
    for (int r = 0; r < 4; r++) {
      unsigned int* d = hwrite + hsub + (q * 4 + r) * 8;
      unsigned val = (tt1 << 16) | (unsigned)f2bf(hv[r]);
      asm volatile("global_store_dword %0, %1, off sc0 sc1" :: "v"(d), "v"(val) : "memory");
    }
    if (t == S_ - 1) {
#pragma unroll
      for (int r = 0; r < 4; r++)
        hfinal[(bt * 16 + q * 4 + r) * H_ + colglob] = hv[r];
    }
    __syncthreads();   // LDS WAR: all waves done reading lds_h before next stage
  }
}

// ---------------------------------------------------------------------------
// VAE head: mu/lv = h@W + b, z = mu + eps*exp(0.5*lv),
// recon = relu(z@dec_w1+db1)@dec_w2+db2. One block per batch row, all fp32.
// ---------------------------------------------------------------------------
__global__ void post_kernel(const float* __restrict__ hfinal, const float* __restrict__ eps,
                            const float* __restrict__ mu_w, const float* __restrict__ mu_b,
                            const float* __restrict__ lv_w, const float* __restrict__ lv_b,
                            const float* __restrict__ dw1, const float* __restrict__ db1,
                            const float* __restrict__ dw2, const float* __restrict__ db2,
                            float* __restrict__ out) {
  __shared__ float sh[H_], sh1[H_], smu[L_], slv[L_], sz[L_];
  int b = blockIdx.x, t = threadIdx.x;
  for (int i = t; i < H_; i += 256) sh[i] = hfinal[b * H_ + i];
  __syncthreads();
  {
    int o = t >> 3, sub = t & 7, l = o & 15;   // 32 outputs x 8-lane partial dots
    const float* w = (o < 16) ? mu_w : lv_w;
    float acc = 0.f;
    int k0 = sub * 64;
#pragma unroll 8
    for (int k = k0; k < k0 + 64; k++) acc = fmaf(sh[k], w[k * L_ + l], acc);
#pragma unroll
    for (int d = 4; d >= 1; d >>= 1) acc += __shfl_down(acc, d, 8);
    if (sub == 0) {
      if (o < 16) { float v = acc + mu_b[l]; smu[l] = v; out[32768 + b * 16 + l] = v; }
      else        { float v = acc + lv_b[l]; slv[l] = v; out[36864 + b * 16 + l] = v; }
    }
  }
  __syncthreads();
  if (t < L_) sz[t] = smu[t] + eps[b * L_ + t] * __expf(0.5f * slv[t]);
  __syncthreads();
  for (int j = t; j < H_; j += 256) {
    float acc = db1[j];
#pragma unroll
    for (int l = 0; l < L_; l++) acc = fmaf(sz[l], dw1[l * H_ + j], acc);
    sh1[j] = fmaxf(acc, 0.f);
  }
  __syncthreads();
  if (t < F_) {
    float acc = db2[t];
    for (int k = 0; k < H_; k++) acc = fmaf(sh1[k], dw2[k * F_ + t], acc);
    out[b * F_ + t] = acc;
  }
}

// ---------------------------------------------------------------------------
extern "C" void kernel_launch(void* const* d_in, const int* in_sizes, int n_in,
                              void* d_out, int out_size, void* d_ws, size_t ws_size,
                              hipStream_t stream) {
  const float* x      = (const float*)d_in[0];
  const float* ctxin  = (const float*)d_in[1];
  const float* eps    = (const float*)d_in[2];
  const float* W_ih   = (const float*)d_in[3];
  const float* b_ih   = (const float*)d_in[4];
  const float* W_hh   = (const float*)d_in[5];
  const float* b_hh   = (const float*)d_in[6];
  const float* cg_w1  = (const float*)d_in[7];
  const float* cg_b1  = (const float*)d_in[8];
  const float* cg_w2  = (const float*)d_in[9];
  const float* cg_b2  = (const float*)d_in[10];
  const float* mu_w   = (const float*)d_in[11];
  const float* mu_b   = (const float*)d_in[12];
  const float* lv_w   = (const float*)d_in[13];
  const float* lv_b   = (const float*)d_in[14];
  const float* dec_w1 = (const float*)d_in[15];
  const float* dec_b1 = (const float*)d_in[16];
  const float* dec_w2 = (const float*)d_in[17];
  const float* dec_b2 = (const float*)d_in[18];
  float* out = (float*)d_out;

  char* ws = (char*)d_ws;
  size_t off = 0;
  auto alloc = [&](size_t bytes) { char* p = ws + off; off = (off + bytes + 255) & ~(size_t)255; return p; };

  unsigned int* hb0 = (unsigned int*)alloc((size_t)B_ * H_ * 4);  // 512 KB tagged dwords
  unsigned int* hb1 = (unsigned int*)alloc((size_t)B_ * H_ * 4);  // 512 KB
  size_t zero_bytes = off;   // zero tags each launch (tag 0 == valid h(-1)=0)
  unsigned short* xfr  = (unsigned short*)alloc((size_t)B_ * S_ * F_ * 2);  // 8 MB
  unsigned short* Wpk  = (unsigned short*)alloc((size_t)H_ * 2048 * 2);     // 2 MB
  unsigned short* Wipk = (unsigned short*)alloc((size_t)F_ * 2048 * 2);     // 512 KB
  float* bc    = (float*)alloc(2048 * 4);
  float* ctxg  = (float*)alloc((size_t)B_ * 1536 * 4);
  float* hid1  = (float*)alloc((size_t)B_ * H_ * 4);
  float* hfin  = (float*)alloc((size_t)B_ * H_ * 4);
  (void)ws_size; (void)in_sizes; (void)n_in; (void)out_size;

  hipMemsetAsync(d_ws, 0, zero_bytes, stream);   // tagged h buffers

  fused_pre<<<2952, 256, 0, stream>>>(W_hh, W_ih, b_ih, b_hh, x, ctxin, cg_w1, cg_b1,
                                      Wpk, Wipk, bc, xfr, hid1);
  ctx2_kernel<<<64, 256, 0, stream>>>(hid1, cg_w2, cg_b2, ctxg);
  lstm_kernel<<<128, 256, 0, stream>>>(xfr, Wpk, Wipk, bc, ctxg, hfin, hb0, hb1);
  post_kernel<<<256, 256, 0, stream>>>(hfin, eps, mu_w, mu_b, lv_w, lv_b,
                                       dec_w1, dec_b1, dec_w2, dec_b2, out);
}

// Round 11
// 624.195 us; speedup vs baseline: 1.1033x; 1.0420x over previous
//
#include <hip/hip_runtime.h>
#include <cstdint>
#include <cstddef>

// Sizes (fixed by the problem)
#define B_ 256
#define S_ 128
#define F_ 128
#define H_ 512
#define C_ 64
#define L_ 16
// 4H = 2048, 3H = 1536

typedef __attribute__((ext_vector_type(8))) short short8;   // 8 x bf16 (4 VGPRs) MFMA A/B frag
typedef __attribute__((ext_vector_type(4))) float f4;       // MFMA C/D frag
typedef __attribute__((ext_vector_type(4))) unsigned int u4;

__device__ __forceinline__ unsigned short f2bf(float f) {   // fp32 -> bf16 RNE
  union { float f; unsigned u; } v; v.f = f;
  unsigned r = v.u + 0x7fffu + ((v.u >> 16) & 1u);
  return (unsigned short)(r >> 16);
}
// v_rcp_f32 is ~1 ulp accurate: error negligible vs bf16 h rounding.
__device__ __forceinline__ float sigmoid_(float x) {
  return __builtin_amdgcn_rcpf(1.0f + __expf(-x));
}
__device__ __forceinline__ float tanh_(float x) {
  x = fminf(15.f, fmaxf(-15.f, x));           // clamp: avoid inf/inf
  float e = __expf(2.f * x);
  return (e - 1.f) * __builtin_amdgcn_rcpf(e + 1.f);
}

// ---------------------------------------------------------------------------
// FUSED pre-pass: prepack W_hh/W_ih + bias fold (blocks [0,648)),
// prepack x (blocks [648,2696)), ctx gate stage 1 (blocks [2696,2952)).
//   W frag(g, w, gate, kit): col = gate*512 + g*64 + w*16 + (lane&15)
//                            k   = kit*32 + ((lane>>4)<<3) + j
// ---------------------------------------------------------------------------
__global__ void fused_pre(const float* __restrict__ W_hh, const float* __restrict__ W_ih,
                          const float* __restrict__ b_ih, const float* __restrict__ b_hh,
                          const float* __restrict__ x, const float* __restrict__ context,
                          const float* __restrict__ cg_w1, const float* __restrict__ cg_b1,
                          unsigned short* __restrict__ Wpk, unsigned short* __restrict__ Wipk,
                          float* __restrict__ bc, unsigned short* __restrict__ xfr,
                          float* __restrict__ hid1) {
  int bid = blockIdx.x;
  if (bid < 648) {                       // ---- prepack weights + bias ----
    int t = bid * blockDim.x + threadIdx.x;
    if (t < 131072) {                    // W_hh: 8 g * 4 w * 4 gate * 16 kit * 64 lanes
      int lane = t & 63, r = t >> 6;
      int kit = r & 15, z = r >> 4;      // z = g*16 + w*4 + gate
      int gate = z & 3, w = (z >> 2) & 3, g = z >> 4;
      int col = gate * 512 + g * 64 + w * 16 + (lane & 15);
      int k0 = kit * 32 + ((lane >> 4) << 3);
#pragma unroll
      for (int j = 0; j < 8; j++)
        Wpk[t * 8 + j] = f2bf(W_hh[(k0 + j) * 2048 + col]);
    } else if (t < 131072 + 32768) {     // W_ih: 8 g * 4 w * 4 gate * 4 kit * 64 lanes
      int t2 = t - 131072;
      int lane = t2 & 63, r = t2 >> 6;
      int kit = r & 3, z = r >> 2;       // z = g*16 + w*4 + gate
      int gate = z & 3, w = (z >> 2) & 3, g = z >> 4;
      int col = gate * 512 + g * 64 + w * 16 + (lane & 15);
      int k0 = kit * 32 + ((lane >> 4) << 3);
#pragma unroll
      for (int j = 0; j < 8; j++)
        Wipk[t2 * 8 + j] = f2bf(W_ih[(k0 + j) * 2048 + col]);
    } else if (t < 131072 + 32768 + 2048) {
      int i = t - 131072 - 32768;
      bc[i] = b_ih[i] + b_hh[i];         // b_ih + b_hh folded together
    }
  } else if (bid < 2696) {               // ---- prepack x (fragment-major bf16) ----
    int o8 = (bid - 648) * blockDim.x + threadIdx.x;   // 524288 chunks
    int m = o8 & 15, kb = (o8 >> 4) & 15, Rg = (o8 >> 8) & 15, s = o8 >> 12;
    int b = Rg * 16 + m;
    const float* src = x + (b * S_ + s) * F_ + kb * 8;
    unsigned short* dst = xfr + o8 * 8;
#pragma unroll
    for (int j = 0; j < 8; j++) dst[j] = f2bf(src[j]);
  } else {                               // ---- ctx1: relu(context @ cg_w1 + b1) ----
    __shared__ float cc[C_];
    int b = bid - 2696, t = threadIdx.x;
    if (t < C_) cc[t] = context[b * C_ + t];
    __syncthreads();
    for (int j = t; j < H_; j += 256) {
      float acc = cg_b1[j];
#pragma unroll 8
      for (int k = 0; k < C_; k++) acc = fmaf(cc[k], cg_w1[k * H_ + j], acc);
      hid1[b * H_ + j] = fmaxf(acc, 0.f);
    }
  }
}

// ---------------------------------------------------------------------------
// Context gate, stage 2: ctxg = sigmoid(hid1 @ cg_w2 + cg_b2)   [256 x 1536]
// ---------------------------------------------------------------------------
__global__ void ctx2_kernel(const float* __restrict__ hid1, const float* __restrict__ w2,
                            const float* __restrict__ b2, float* __restrict__ ctxg) {
  __shared__ float hr[4 * H_];
  int r0 = blockIdx.x * 4, t = threadIdx.x;
  for (int i = t; i < 4 * H_; i += 256) hr[i] = hid1[r0 * H_ + i];
  __syncthreads();
  float acc[4][6];
#pragma unroll
  for (int r = 0; r < 4; r++)
#pragma unroll
    for (int i = 0; i < 6; i++) acc[r][i] = 0.f;
  for (int k = 0; k < H_; k++) {
    float w[6];
#pragma unroll
    for (int i = 0; i < 6; i++) w[i] = w2[k * 1536 + t + i * 256];
#pragma unroll
    for (int r = 0; r < 4; r++) {
      float hv = hr[r * H_ + k];
#pragma unroll
      for (int i = 0; i < 6; i++) acc[r][i] = fmaf(hv, w[i], acc[r][i]);
    }
  }
#pragma unroll
  for (int r = 0; r < 4; r++)
#pragma unroll
    for (int i = 0; i < 6; i++) {
      int col = t + i * 256;
      ctxg[(r0 + r) * 1536 + col] = 1.0f / (1.0f + __expf(-(acc[r][i] + b2[col])));
    }
}

// ---------------------------------------------------------------------------
// Persistent LSTM kernel. Grid = 128 blocks = 16 batch-groups (16 rows) x
// 8 col-blocks (64 h-cols). Wave w owns ALL FOUR gates for its 16 columns ->
// in-register cell update.
// TAGGED-DWORD h EXCHANGE with PARTIAL RE-POLL:
//   h element = dword (tag<<16)|bf16, tag = step t+1, fire-and-forget at
//   device scope (sc0 sc1). Round 1 loads all 8 dwordx4 (self-contained asm,
//   internal vmcnt(0) -> spill-safe). Tags are MONOTONE per buffer pass, so
//   a quarter that reads fresh is FINAL -> retry rounds reload only stale
//   quarters via one predicated asm block (SGPR mask + s_bitcmp1/s_cbranch,
//   internal vmcnt(0) -> still spill-safe; between asms no load in flight).
//   s_sleep(2) backoff between rounds cuts contention. WAR across the
//   2-buffer reuse ordered by dataflow causality (tags unique per reuse).
// SINGLE barrier per step: lds_h double-buffered; stage(t+1) targets the
//   other half, and a wave reaches stage(t+2) of a given half only after
//   the t+1 barrier, which follows all t reads of that half.
// ---------------------------------------------------------------------------
__global__ void __launch_bounds__(256, 1) lstm_kernel(
    const unsigned short* __restrict__ xfr, const unsigned short* __restrict__ Wpk,
    const unsigned short* __restrict__ Wipk, const float* __restrict__ bc,
    const float* __restrict__ ctxg, float* __restrict__ hfinal,
    unsigned int* __restrict__ hb0, unsigned int* __restrict__ hb1) {
  __shared__ __align__(16) unsigned short lds_h[2][8192];  // 2 x 16 kit x 512 (32 KB)

  int tid = threadIdx.x, lane = tid & 63, wid = tid >> 6;
  int bt = blockIdx.x >> 3, g = blockIdx.x & 7;

  // --- prologue: resident weight fragments (coalesced 16B/lane loads) ---
  short8 wf[4][16], wfi[4][4];
#pragma unroll
  for (int gate = 0; gate < 4; gate++) {
    const short8* wp = (const short8*)Wpk + (size_t)((g * 16 + wid * 4 + gate) * 16) * 64 + lane;
#pragma unroll
    for (int kit = 0; kit < 16; kit++) wf[gate][kit] = wp[kit * 64];
    const short8* wip = (const short8*)Wipk + (size_t)((g * 16 + wid * 4 + gate) * 4) * 64 + lane;
#pragma unroll
    for (int kit = 0; kit < 4; kit++) wfi[gate][kit] = wip[kit * 64];
  }

  // --- per-lane elementwise constants: lane (q,n) owns rows q*4+r, col n ---
  int q = lane >> 4, n = lane & 15;
  int colglob = g * 64 + wid * 16 + n;
  float ci_[4], cf_[4], co_[4], cst[4] = {0.f, 0.f, 0.f, 0.f};
#pragma unroll
  for (int r = 0; r < 4; r++) {
    int brow = bt * 16 + q * 4 + r;
    ci_[r] = ctxg[brow * 1536 + colglob];
    cf_[r] = ctxg[brow * 1536 + 512 + colglob];
    co_[r] = ctxg[brow * 1536 + 1024 + colglob];
  }
  float bi = bc[colglob], bff = bc[512 + colglob], bgg = bc[1024 + colglob], bo = bc[1536 + colglob];

  // fragment-order store base for this lane's column (units: dwords).
  int hsub = (bt * 16 + (colglob >> 5)) * 512 + ((colglob >> 3) & 3) * 128 + (colglob & 7);

  for (int t = 0; t < S_; t++) {
    const unsigned int* hread = (t & 1) ? hb1 : hb0;   // double buffer
    unsigned int* hwrite = (t & 1) ? hb0 : hb1;
    int cur = t & 1;
    unsigned tt = (unsigned)t;          // expected tag on consumed data
    unsigned tt1 = (unsigned)(t + 1);   // tag stored with produced data

    // --- x fragments for step t: plain cached loads (fly under the poll) ---
    u4 xt[4];
#pragma unroll
    for (int kit = 0; kit < 4; kit++)
      xt[kit] = *(const u4*)(xfr + ((size_t)(t * 16 + bt) * 4 + kit) * 512 + lane * 8);

    // --- poll own 4 kit rows of h(t-1): full round 1, partial retries ---
    u4 a0, a1, a2, a3, a4, a5, a6, a7;
    {
      const unsigned int* base = hread + (bt * 16 + wid * 4) * 512 + lane * 8;
      const unsigned int* p0 = base;
      const unsigned int* p1 = base + 4;
      const unsigned int* p2 = base + 512;
      const unsigned int* p3 = base + 516;
      const unsigned int* p4 = base + 1024;
      const unsigned int* p5 = base + 1028;
      const unsigned int* p6 = base + 1536;
      const unsigned int* p7 = base + 1540;
      asm volatile(
          "global_load_dwordx4 %0, %8, off sc0 sc1\n\t"
          "global_load_dwordx4 %1, %9, off sc0 sc1\n\t"
          "global_load_dwordx4 %2, %10, off sc0 sc1\n\t"
          "global_load_dwordx4 %3, %11, off sc0 sc1\n\t"
          "global_load_dwordx4 %4, %12, off sc0 sc1\n\t"
          "global_load_dwordx4 %5, %13, off sc0 sc1\n\t"
          "global_load_dwordx4 %6, %14, off sc0 sc1\n\t"
          "global_load_dwordx4 %7, %15, off sc0 sc1\n\t"
          "s_waitcnt vmcnt(0)"
          : "=&v"(a0), "=&v"(a1), "=&v"(a2), "=&v"(a3),
            "=&v"(a4), "=&v"(a5), "=&v"(a6), "=&v"(a7)
          : "v"(p0), "v"(p1), "v"(p2), "v"(p3),
            "v"(p4), "v"(p5), "v"(p6), "v"(p7)
          : "memory");
      auto bad = [&](const u4& a) -> unsigned {
        return ((a[0] >> 16) ^ tt) | ((a[1] >> 16) ^ tt)
             | ((a[2] >> 16) ^ tt) | ((a[3] >> 16) ^ tt);
      };
      unsigned m = (__any((int)(bad(a0) != 0)) ? 1u : 0u)
                 | (__any((int)(bad(a1) != 0)) ? 2u : 0u)
                 | (__any((int)(bad(a2) != 0)) ? 4u : 0u)
                 | (__any((int)(bad(a3) != 0)) ? 8u : 0u)
                 | (__any((int)(bad(a4) != 0)) ? 16u : 0u)
                 | (__any((int)(bad(a5) != 0)) ? 32u : 0u)
                 | (__any((int)(bad(a6) != 0)) ? 64u : 0u)
                 | (__any((int)(bad(a7) != 0)) ? 128u : 0u);
      while (m) {
        __builtin_amdgcn_s_sleep(2);   // ~128 cy backoff: cut poll contention
        asm volatile(
            "s_bitcmp1_b32 %16, 0\n\t"
            "s_cbranch_scc0 Lp0_%=\n\t"
            "global_load_dwordx4 %0, %8, off sc0 sc1\n"
            "Lp0_%=:\n\t"
            "s_bitcmp1_b32 %16, 1\n\t"
            "s_cbranch_scc0 Lp1_%=\n\t"
            "global_load_dwordx4 %1, %9, off sc0 sc1\n"
            "Lp1_%=:\n\t"
            "s_bitcmp1_b32 %16, 2\n\t"
            "s_cbranch_scc0 Lp2_%=\n\t"
            "global_load_dwordx4 %2, %10, off sc0 sc1\n"
            "Lp2_%=:\n\t"
            "s_bitcmp1_b32 %16, 3\n\t"
            "s_cbranch_scc0 Lp3_%=\n\t"
            "global_load_dwordx4 %3, %11, off sc0 sc1\n"
            "Lp3_%=:\n\t"
            "s_bitcmp1_b32 %16, 4\n\t"
            "s_cbranch_scc0 Lp4_%=\n\t"
            "global_load_dwordx4 %4, %12, off sc0 sc1\n"
            "Lp4_%=:\n\t"
            "s_bitcmp1_b32 %16, 5\n\t"
            "s_cbranch_scc0 Lp5_%=\n\t"
            "global_load_dwordx4 %5, %13, off sc0 sc1\n"
            "Lp5_%=:\n\t"
            "s_bitcmp1_b32 %16, 6\n\t"
            "s_cbranch_scc0 Lp6_%=\n\t"
            "global_load_dwordx4 %6, %14, off sc0 sc1\n"
            "Lp6_%=:\n\t"
            "s_bitcmp1_b32 %16, 7\n\t"
            "s_cbranch_scc0 Lp7_%=\n\t"
            "global_load_dwordx4 %7, %15, off sc0 sc1\n"
            "Lp7_%=:\n\t"
            "s_waitcnt vmcnt(0)"
            : "+v"(a0), "+v"(a1), "+v"(a2), "+v"(a3),
              "+v"(a4), "+v"(a5), "+v"(a6), "+v"(a7)
            : "v"(p0), "v"(p1), "v"(p2), "v"(p3),
              "v"(p4), "v"(p5), "v"(p6), "v"(p7), "s"(m)
            : "memory", "scc");
        m = (__any((int)(bad(a0) != 0)) ? 1u : 0u)
          | (__any((int)(bad(a1) != 0)) ? 2u : 0u)
          | (__any((int)(bad(a2) != 0)) ? 4u : 0u)
          | (__any((int)(bad(a3) != 0)) ? 8u : 0u)
          | (__any((int)(bad(a4) != 0)) ? 16u : 0u)
          | (__any((int)(bad(a5) != 0)) ? 32u : 0u)
          | (__any((int)(bad(a6) != 0)) ? 64u : 0u)
          | (__any((int)(bad(a7) != 0)) ? 128u : 0u);
      }
    }

    // --- strip tags, pack to bf16x8, stage own 4 rows into lds_h[cur] ---
    {
      unsigned short* lh = &lds_h[cur][0];
      u4 P;
      P.x = (a0[0] & 0xffffu) | (a0[1] << 16);
      P.y = (a0[2] & 0xffffu) | (a0[3] << 16);
      P.z = (a1[0] & 0xffffu) | (a1[1] << 16);
      P.w = (a1[2] & 0xffffu) | (a1[3] << 16);
      *(u4*)(lh + (wid * 4 + 0) * 512 + lane * 8) = P;
      P.x = (a2[0] & 0xffffu) | (a2[1] << 16);
      P.y = (a2[2] & 0xffffu) | (a2[3] << 16);
      P.z = (a3[0] & 0xffffu) | (a3[1] << 16);
      P.w = (a3[2] & 0xffffu) | (a3[3] << 16);
      *(u4*)(lh + (wid * 4 + 1) * 512 + lane * 8) = P;
      P.x = (a4[0] & 0xffffu) | (a4[1] << 16);
      P.y = (a4[2] & 0xffffu) | (a4[3] << 16);
      P.z = (a5[0] & 0xffffu) | (a5[1] << 16);
      P.w = (a5[2] & 0xffffu) | (a5[3] << 16);
      *(u4*)(lh + (wid * 4 + 2) * 512 + lane * 8) = P;
      P.x = (a6[0] & 0xffffu) | (a6[1] << 16);
      P.y = (a6[2] & 0xffffu) | (a6[3] << 16);
      P.z = (a7[0] & 0xffffu) | (a7[1] << 16);
      P.w = (a7[2] & 0xffffu) | (a7[3] << 16);
      *(u4*)(lh + (wid * 4 + 3) * 512 + lane * 8) = P;
    }
    __syncthreads();   // the ONLY barrier: stage(cur) complete before reads

    // --- x MFMAs ---
    f4 acc[4];
#pragma unroll
    for (int gate = 0; gate < 4; gate++) acc[gate] = (f4){0.f, 0.f, 0.f, 0.f};
#pragma unroll
    for (int kit = 0; kit < 4; kit++) {
      short8 a = __builtin_bit_cast(short8, xt[kit]);
#pragma unroll
      for (int gate = 0; gate < 4; gate++)
        acc[gate] = __builtin_amdgcn_mfma_f32_16x16x32_bf16(a, wfi[gate][kit], acc[gate], 0, 0, 0);
    }

    // --- h MFMAs: all 4 gates for this wave's 16 columns ---
#pragma unroll
    for (int kit = 0; kit < 16; kit++) {
      short8 a = *(const short8*)(&lds_h[cur][0] + kit * 512 + lane * 8);
#pragma unroll
      for (int gate = 0; gate < 4; gate++)
        acc[gate] = __builtin_amdgcn_mfma_f32_16x16x32_bf16(a, wf[gate][kit], acc[gate], 0, 0, 0);
    }

    // --- cell update fully in-register (all 4 gates lane-local) ---
    float hv[4];
#pragma unroll
    for (int r = 0; r < 4; r++) {
      float gi = acc[0][r] + bi, gf = acc[1][r] + bff, gc = acc[2][r] + bgg, go = acc[3][r] + bo;
      float iv = ci_[r] * sigmoid_(gi);
      float fv = cf_[r] * sigmoid_(gf);
      float ov = co_[r] * sigmoid_(go);
      float gv = tanh_(gc);
      float c = fv * cst[r] + iv * gv;
      cst[r] = c;
      hv[r] = ov * tanh_(c);
    }

    // --- tagged fragment-order h store: 4 dwords/lane, fire-and-forget ---
#pragma unroll
    for (int r = 0; r < 4; r++) {
      unsigned int* d = hwrite + hsub + (q * 4 + r) * 8;
      unsigned val = (tt1 << 16) | (unsigned)f2bf(hv[r]);
      asm volatile("global_store_dword %0, %1, off sc0 sc1" :: "v"(d), "v"(val) : "memory");
    }
    if (t == S_ - 1) {
#pragma unroll
      for (int r = 0; r < 4; r++)
        hfinal[(bt * 16 + q * 4 + r) * H_ + colglob] = hv[r];
    }
    // no end-of-step barrier: next stage targets lds_h[cur^1]
  }
}

// ---------------------------------------------------------------------------
// VAE head: mu/lv = h@W + b, z = mu + eps*exp(0.5*lv),
// recon = relu(z@dec_w1+db1)@dec_w2+db2. One block per batch row, all fp32.
// ---------------------------------------------------------------------------
__global__ void post_kernel(const float* __restrict__ hfinal, const float* __restrict__ eps,
                            const float* __restrict__ mu_w, const float* __restrict__ mu_b,
                            const float* __restrict__ lv_w, const float* __restrict__ lv_b,
                            const float* __restrict__ dw1, const float* __restrict__ db1,
                            const float* __restrict__ dw2, const float* __restrict__ db2,
                            float* __restrict__ out) {
  __shared__ float sh[H_], sh1[H_], smu[L_], slv[L_], sz[L_];
  int b = blockIdx.x, t = threadIdx.x;
  for (int i = t; i < H_; i += 256) sh[i] = hfinal[b * H_ + i];
  __syncthreads();
  {
    int o = t >> 3, sub = t & 7, l = o & 15;   // 32 outputs x 8-lane partial dots
    const float* w = (o < 16) ? mu_w : lv_w;
    float acc = 0.f;
    int k0 = sub * 64;
#pragma unroll 8
    for (int k = k0; k < k0 + 64; k++) acc = fmaf(sh[k], w[k * L_ + l], acc);
#pragma unroll
    for (int d = 4; d >= 1; d >>= 1) acc += __shfl_down(acc, d, 8);
    if (sub == 0) {
      if (o < 16) { float v = acc + mu_b[l]; smu[l] = v; out[32768 + b * 16 + l] = v; }
      else        { float v = acc + lv_b[l]; slv[l] = v; out[36864 + b * 16 + l] = v; }
    }
  }
  __syncthreads();
  if (t < L_) sz[t] = smu[t] + eps[b * L_ + t] * __expf(0.5f * slv[t]);
  __syncthreads();
  for (int j = t; j < H_; j += 256) {
    float acc = db1[j];
#pragma unroll
    for (int l = 0; l < L_; l++) acc = fmaf(sz[l], dw1[l * H_ + j], acc);
    sh1[j] = fmaxf(acc, 0.f);
  }
  __syncthreads();
  if (t < F_) {
    float acc = db2[t];
    for (int k = 0; k < H_; k++) acc = fmaf(sh1[k], dw2[k * F_ + t], acc);
    out[b * F_ + t] = acc;
  }
}

// ---------------------------------------------------------------------------
extern "C" void kernel_launch(void* const* d_in, const int* in_sizes, int n_in,
                              void* d_out, int out_size, void* d_ws, size_t ws_size,
                              hipStream_t stream) {
  const float* x      = (const float*)d_in[0];
  const float* ctxin  = (const float*)d_in[1];
  const float* eps    = (const float*)d_in[2];
  const float* W_ih   = (const float*)d_in[3];
  const float* b_ih   = (const float*)d_in[4];
  const float* W_hh   = (const float*)d_in[5];
  const float* b_hh   = (const float*)d_in[6];
  const float* cg_w1  = (const float*)d_in[7];
  const float* cg_b1  = (const float*)d_in[8];
  const float* cg_w2  = (const float*)d_in[9];
  const float* cg_b2  = (const float*)d_in[10];
  const float* mu_w   = (const float*)d_in[11];
  const float* mu_b   = (const float*)d_in[12];
  const float* lv_w   = (const float*)d_in[13];
  const float* lv_b   = (const float*)d_in[14];
  const float* dec_w1 = (const float*)d_in[15];
  const float* dec_b1 = (const float*)d_in[16];
  const float* dec_w2 = (const float*)d_in[17];
  const float* dec_b2 = (const float*)d_in[18];
  float* out = (float*)d_out;

  char* ws = (char*)d_ws;
  size_t off = 0;
  auto alloc = [&](size_t bytes) { char* p = ws + off; off = (off + bytes + 255) & ~(size_t)255; return p; };

  unsigned int* hb0 = (unsigned int*)alloc((size_t)B_ * H_ * 4);  // 512 KB tagged dwords
  unsigned int* hb1 = (unsigned int*)alloc((size_t)B_ * H_ * 4);  // 512 KB
  size_t zero_bytes = off;   // zero tags each launch (tag 0 == valid h(-1)=0)
  unsigned short* xfr  = (unsigned short*)alloc((size_t)B_ * S_ * F_ * 2);  // 8 MB
  unsigned short* Wpk  = (unsigned short*)alloc((size_t)H_ * 2048 * 2);     // 2 MB
  unsigned short* Wipk = (unsigned short*)alloc((size_t)F_ * 2048 * 2);     // 512 KB
  float* bc    = (float*)alloc(2048 * 4);
  float* ctxg  = (float*)alloc((size_t)B_ * 1536 * 4);
  float* hid1  = (float*)alloc((size_t)B_ * H_ * 4);
  float* hfin  = (float*)alloc((size_t)B_ * H_ * 4);
  (void)ws_size; (void)in_sizes; (void)n_in; (void)out_size;

  hipMemsetAsync(d_ws, 0, zero_bytes, stream);   // tagged h buffers

  fused_pre<<<2952, 256, 0, stream>>>(W_hh, W_ih, b_ih, b_hh, x, ctxin, cg_w1, cg_b1,
                                      Wpk, Wipk, bc, xfr, hid1);
  ctx2_kernel<<<64, 256, 0, stream>>>(hid1, cg_w2, cg_b2, ctxg);
  lstm_kernel<<<128, 256, 0, stream>>>(xfr, Wpk, Wipk, bc, ctxg, hfin, hb0, hb1);
  post_kernel<<<256, 256, 0, stream>>>(hfin, eps, mu_w, mu_b, lv_w, lv_b,
                                       dec_w1, dec_b1, dec_w2, dec_b2, out);
}